// Round 15
// baseline (325.782 us; speedup 1.0000x reference)
//
#include <hip/hip_runtime.h>

typedef unsigned short ushort_t;
typedef unsigned int uint32;
typedef __attribute__((ext_vector_type(8))) short short8;
typedef __attribute__((ext_vector_type(4))) float f32x4;
typedef __attribute__((ext_vector_type(2))) float f32x2;

#define LOG2E   1.4426950408889634f
#define LOG2E2  2.8853900817779268f
#define MFMA16  __builtin_amdgcn_mfma_f32_16x16x32_bf16

static __device__ __forceinline__ ushort_t f2bf(float f) {
    uint32 u = __float_as_uint(f);
    u += 0x7FFFu + ((u >> 16) & 1u);
    return (ushort_t)(u >> 16);
}
static __device__ __forceinline__ float rcp_(float x) { return __builtin_amdgcn_rcpf(x); }
static __device__ __forceinline__ float ex2_(float x) { return __builtin_amdgcn_exp2f(x); }
// sigmoid with pre-scaled arg (x already multiplied by log2e)
static __device__ __forceinline__ float sigp_(float x) { return rcp_(1.0f + ex2_(-x)); }

// LDS-only block sync: does NOT drain vmcnt -> global stores float across steps.
static __device__ __forceinline__ void bar_lds() {
    asm volatile("s_waitcnt lgkmcnt(0)" ::: "memory");
    __builtin_amdgcn_s_barrier();
}
// Full sync: drains vmem too. Used every 4 producer steps; stores are >= 1 step
// old by then (aged at top-of-step) -> the wait is ~free.
static __device__ __forceinline__ void bar_full() {
    asm volatile("s_waitcnt vmcnt(0) lgkmcnt(0)" ::: "memory");
    __builtin_amdgcn_s_barrier();
}

// ---------------- prep: pack W into MFMA A-fragments (16-wave / 2-tile geometry) ----
template<int LAYER>
__global__ void prep_frag(const float* __restrict__ Whh, const float* __restrict__ Wih,
                          ushort_t* __restrict__ wfrag) {
    constexpr int KT  = (LAYER == 0) ? 6 : 8;
    constexpr int DIN = (LAYER == 0) ? 64 : 128;
    int i = blockIdx.x * 256 + threadIdx.x;
    int e    = i & 7;
    int lam  = (i >> 3) & 63;
    int rest = i >> 9;
    int kt    = rest % KT;
    int rest2 = rest / KT;
    int tt = rest2 & 1;
    int w  = rest2 >> 1;
    if (w >= 16) return;
    int ml = lam & 15;
    int kg = lam >> 4;
    int k  = kt * 32 + kg * 8 + e;
    int r  = ml & 3;
    int hc = 8 * w + 2 * (ml >> 2) + tt;
    int row = r * 128 + hc;
    float scale = (r == 2) ? LOG2E2 : LOG2E;
    float v = (k < 128) ? Whh[row * 128 + k] : Wih[row * DIN + (k - 128)];
    wfrag[i] = f2bf(v * scale);
}

__global__ void prep_bias(const float* __restrict__ bih0, const float* __restrict__ bhh0,
                          const float* __restrict__ bih1, const float* __restrict__ bhh1,
                          float* __restrict__ bp0, float* __restrict__ bp1,
                          uint32* __restrict__ flags) {
    int i = blockIdx.x * 256 + threadIdx.x;   // 0..1023
    flags[i] = 0u;                            // reset pipeline flags (graph-replay safe)
    flags[i + 1024] = 0u;
    int p = i & 511;
    int w = p >> 5, tt = (p >> 4) & 1, ml = p & 15;
    int r = ml & 3;
    int hc = 8 * w + 2 * (ml >> 2) + tt;
    int row = r * 128 + hc;
    float scale = (r == 2) ? LOG2E2 : LOG2E;
    if (i < 512) bp0[p] = (bih0[row] + bhh0[row]) * scale;
    else         bp1[p] = (bih1[row] + bhh1[row]) * scale;
}

// ---------------- pipelined 2-layer LSTM: drain-free steps, aged stores, 4-step flags ----
// 128 blocks x 1024 threads (16 waves -> 4 waves/SIMD latency self-hiding).
// Blocks 0..63 = L0 producer, 64..127 = L1 consumer (same batch group, same XCD
// under round-robin since 64 % 8 == 0).
// Producer: record h[T-1] stored at TOP of step T (one-register delay); every 4
// steps bar_full() (stores >= 1 step old -> free) + flag = T (claims records <= T-1).
// Consumer: step t needs flag >= t+2; prologue waits flag >= 12 (13 us fill,
// initial lead 12-16 > quantization bound 5 -> steady state near-zero polls).
template<int KT, bool IS_L0>
__device__ __forceinline__ void run_phase(
    const int blk,
    const float* __restrict__ xin_f32,     // IS_L0: [B,T,64] f32
    const uint32* __restrict__ xin_rec,    // !IS_L0: k-major records
    const ushort_t* __restrict__ wfrag,
    const float* __restrict__ biasp,
    uint32* __restrict__ hout,             // IS_L0 out
    float* __restrict__ lastH,             // !IS_L0 out
    uint32* __restrict__ flagp,
    ushort_t* hb, ushort_t* xb)
{
    constexpr int KX = KT - 4;
    const int tid  = threadIdx.x;
    const int w    = tid >> 6;
    const int lane = tid & 63;
    const int n    = lane & 15;
    const int kg   = lane >> 4;
    const int b0   = blk * 16;

    // weights -> registers (held entire kernel)
    short8 wf[2][KT];
#pragma unroll
    for (int tt = 0; tt < 2; ++tt)
#pragma unroll
        for (int kt = 0; kt < KT; ++kt)
            wf[tt][kt] = *(const short8*)&wfrag[((((w * 2 + tt) * KT) + kt) * 64 + lane) * 8];

    const f32x4 bias0 = *(const f32x4*)&biasp[w * 32 + kg * 4];
    const f32x4 bias1 = *(const f32x4*)&biasp[w * 32 + 16 + kg * 4];

    float cc0 = 0.f, cc1 = 0.f;
    const int hc0 = 8 * w + 2 * kg;        // thread's two h-cols: hc0, hc0+1

    // staging maps
    const int ns  = (tid >> 3) & 15;
    const int kk  = (tid >> 9) * 32 + ((tid >> 7) & 3) * 8 + (tid & 7);
    const long xbase0 = (long)(b0 + ns) * (256 * 64) + kk;
    const long rb     = (long)blk * (256 * 1024);            // u32 units

    uint32*       stp = &hout[rb + w * 64 + n * 4 + kg];     // producer: record 0 slot
    const uint32* ldp = IS_L0 ? nullptr : &xin_rec[rb + 1024 + tid];  // consumer: record 1
    uint32 lastF = 0;
    uint32 prev_hp = 0;                    // producer: h[T-1] packed (stored at top of T)

    // prologue: zero h state (parity 0), stage x/rec[0]
    ((uint32*)hb)[tid] = 0u;
    if constexpr (IS_L0) {
        xb[tid] = f2bf(xin_f32[xbase0]);
    } else {
        lastF = __hip_atomic_load(flagp, __ATOMIC_ACQUIRE, __HIP_MEMORY_SCOPE_AGENT);
        while (lastF < 12u) {              // built-in ~12-16 step producer head start
            __builtin_amdgcn_s_sleep(8);
            lastF = __hip_atomic_load(flagp, __ATOMIC_ACQUIRE, __HIP_MEMORY_SCOPE_AGENT);
        }
        ((uint32*)xb)[tid] = __hip_atomic_load(&xin_rec[rb + tid],
                                __ATOMIC_RELAXED, __HIP_MEMORY_SCOPE_AGENT);
    }
    __syncthreads();

#define STEP(CUR, NXT, T)                                                          \
    {                                                                              \
        /* producer: store record h[T-1] FIRST (ages a full step before drain) */  \
        if (IS_L0 && (T) > 0) {                                                    \
            __hip_atomic_store(stp, prev_hp, __ATOMIC_RELAXED, __HIP_MEMORY_SCOPE_AGENT); \
            stp += 1024;                                                           \
        }                                                                          \
        const bool pf = ((T) + 1 < 256);                                           \
        float xf = 0.f; uint32 xu = 0;                                             \
        if (pf) {                                                                  \
            if (IS_L0) {                                                           \
                xf = xin_f32[xbase0 + ((T) + 1) * 64];                             \
            } else {                                                               \
                const uint32 want = (uint32)((T) + 2);   /* record T+1 */          \
                if (lastF < want) {                                                \
                    lastF = __hip_atomic_load(flagp, __ATOMIC_ACQUIRE, __HIP_MEMORY_SCOPE_AGENT); \
                    while (lastF < want) {                                         \
                        __builtin_amdgcn_s_sleep(4);                               \
                        lastF = __hip_atomic_load(flagp, __ATOMIC_ACQUIRE, __HIP_MEMORY_SCOPE_AGENT); \
                    }                                                              \
                }                                                                  \
                xu = __hip_atomic_load(ldp, __ATOMIC_RELAXED, __HIP_MEMORY_SCOPE_AGENT); \
                ldp += 1024;                                                       \
            }                                                                      \
        }                                                                          \
        short8 bfr0 = *(const short8*)&hb[(CUR) * 2048 + kg * 128 + n * 8];        \
        f32x4 acc0 = MFMA16(wf[0][0], bfr0, bias0, 0, 0, 0);                       \
        f32x4 acc1 = MFMA16(wf[1][0], bfr0, bias1, 0, 0, 0);                       \
        _Pragma("unroll")                                                          \
        for (int kt = 1; kt < 4; ++kt) {                                           \
            short8 bfr = *(const short8*)&hb[(CUR) * 2048 + kt * 512 + kg * 128 + n * 8]; \
            acc0 = MFMA16(wf[0][kt], bfr, acc0, 0, 0, 0);                          \
            acc1 = MFMA16(wf[1][kt], bfr, acc1, 0, 0, 0);                          \
        }                                                                          \
        _Pragma("unroll")                                                          \
        for (int kx = 0; kx < KX; ++kx) {                                          \
            short8 bfr = *(const short8*)&xb[(CUR) * (KX * 512) + kx * 512 + kg * 128 + n * 8]; \
            acc0 = MFMA16(wf[0][4 + kx], bfr, acc0, 0, 0, 0);                      \
            acc1 = MFMA16(wf[1][4 + kx], bfr, acc1, 0, 0, 0);                      \
        }                                                                          \
        float i0 = sigp_(acc0[0]);                                                 \
        float f0 = sigp_(acc0[1]);                                                 \
        float tg0 = fmaf(2.f, sigp_(acc0[2]), -1.f);                               \
        float o0 = sigp_(acc0[3]);                                                 \
        cc0 = fmaf(f0, cc0, i0 * tg0);                                             \
        float h0 = o0 * fmaf(2.f, sigp_(cc0 * LOG2E2), -1.f);                      \
        float i1 = sigp_(acc1[0]);                                                 \
        float f1 = sigp_(acc1[1]);                                                 \
        float tg1 = fmaf(2.f, sigp_(acc1[2]), -1.f);                               \
        float o1 = sigp_(acc1[3]);                                                 \
        cc1 = fmaf(f1, cc1, i1 * tg1);                                             \
        float h1v = o1 * fmaf(2.f, sigp_(cc1 * LOG2E2), -1.f);                     \
        uint32 hp;                                                                 \
        asm("v_cvt_pk_bf16_f32 %0, %1, %2" : "=v"(hp) : "v"(h0), "v"(h1v));        \
        *(uint32*)&hb[(NXT) * 2048 + w * 128 + n * 8 + kg * 2] = hp;               \
        if (IS_L0) prev_hp = hp;                                                   \
        if (!IS_L0 && (T) == 255) {                                                \
            f32x2 hv2 = {h0, h1v};                                                 \
            *(f32x2*)&lastH[(long)(b0 + n) * 128 + hc0] = hv2;                     \
        }                                                                          \
        if (pf) {                                                                  \
            if (IS_L0) xb[(NXT) * (KX * 512) + tid] = f2bf(xf);                    \
            else       ((uint32*)xb)[(NXT) * (KX * 256) + tid] = xu;               \
        }                                                                          \
        if (IS_L0 && ((T) & 3) == 0 && (T) > 0) {                                  \
            /* drain (stores >= 1 step old -> ~free) + publish flag = T */         \
            bar_full();                                                            \
            if (tid == 0)                                                          \
                __hip_atomic_store(flagp, (uint32)(T), __ATOMIC_RELEASE, __HIP_MEMORY_SCOPE_AGENT); \
        } else {                                                                   \
            bar_lds();                                                             \
        }                                                                          \
    }

#pragma unroll 1
    for (int t = 0; t < 256; t += 2) {
        STEP(0, 1, t)
        STEP(1, 0, t + 1)
    }
#undef STEP

    if constexpr (IS_L0) {
        // final record h[255], full drain, terminal flag
        __hip_atomic_store(stp, prev_hp, __ATOMIC_RELAXED, __HIP_MEMORY_SCOPE_AGENT);
        bar_full();
        if (tid == 0)
            __hip_atomic_store(flagp, 1000u, __ATOMIC_RELEASE, __HIP_MEMORY_SCOPE_AGENT);
    }
}

__global__ __launch_bounds__(1024)
void lstm_pipe(const float* __restrict__ x,
               const ushort_t* __restrict__ wf0, const ushort_t* __restrict__ wf1,
               const float* __restrict__ bp0, const float* __restrict__ bp1,
               uint32* __restrict__ h1k, float* __restrict__ lastH,
               uint32* __restrict__ flags)
{
    __shared__ ushort_t hb[4096];   // 8 KiB: h double buffer
    __shared__ ushort_t xb[4096];   // 8 KiB: x double buffer (L0 uses half)
    const int blk = blockIdx.x;
    if (blk < 64)
        run_phase<6, true >(blk, x, nullptr, wf0, bp0, h1k, nullptr,
                            &flags[blk * 32], hb, xb);
    else
        run_phase<8, false>(blk - 64, nullptr, h1k, wf1, bp1, nullptr, lastH,
                            &flags[(blk - 64) * 32], hb, xb);
}

// ---------------- head: LayerNorm + fc1(relu) + fc2 ----------------
__global__ __launch_bounds__(256)
void head_kernel(const float* __restrict__ lastH,
                 const float* __restrict__ ln_g, const float* __restrict__ ln_b,
                 const float* __restrict__ fc1w, const float* __restrict__ fc1b,
                 const float* __restrict__ fc2w, const float* __restrict__ fc2b,
                 float* __restrict__ out) {
    __shared__ float ylds[4][128];
    int w = threadIdx.x >> 6, lane = threadIdx.x & 63;
    int row = blockIdx.x * 4 + w;
    float x0 = lastH[row * 128 + lane];
    float x1 = lastH[row * 128 + 64 + lane];
    float s = x0 + x1;
    for (int off = 32; off; off >>= 1) s += __shfl_xor(s, off);
    float mu = s * (1.f / 128.f);
    float d0 = x0 - mu, d1 = x1 - mu;
    float v = d0 * d0 + d1 * d1;
    for (int off = 32; off; off >>= 1) v += __shfl_xor(v, off);
    float rs = rsqrtf(v * (1.f / 128.f) + 1e-5f);
    ylds[w][lane]      = d0 * rs * ln_g[lane]      + ln_b[lane];
    ylds[w][lane + 64] = d1 * rs * ln_g[lane + 64] + ln_b[lane + 64];
    __syncthreads();
    float a = fc1b[lane];
#pragma unroll 4
    for (int k = 0; k < 128; ++k) a += ylds[w][k] * fc1w[lane * 128 + k];
    float r = fmaxf(a, 0.f) * fc2w[lane];
    for (int off = 32; off; off >>= 1) r += __shfl_xor(r, off);
    if (lane == 0) out[row] = r + fc2b[0];
}

extern "C" void kernel_launch(void* const* d_in, const int* in_sizes, int n_in,
                              void* d_out, int out_size, void* d_ws, size_t ws_size,
                              hipStream_t stream) {
    const float* x    = (const float*)d_in[0];
    const float* Wih0 = (const float*)d_in[1];
    const float* Whh0 = (const float*)d_in[2];
    const float* bih0 = (const float*)d_in[3];
    const float* bhh0 = (const float*)d_in[4];
    const float* Wih1 = (const float*)d_in[5];
    const float* Whh1 = (const float*)d_in[6];
    const float* bih1 = (const float*)d_in[7];
    const float* bhh1 = (const float*)d_in[8];
    const float* ln_g = (const float*)d_in[9];
    const float* ln_b = (const float*)d_in[10];
    const float* fc1w = (const float*)d_in[11];
    const float* fc1b = (const float*)d_in[12];
    const float* fc2w = (const float*)d_in[13];
    const float* fc2b = (const float*)d_in[14];

    char* ws = (char*)d_ws;
    uint32*   h1k   = (uint32*)  (ws);                 // 64 blk x 256 t x 4 KiB = 64 MiB
    ushort_t* wf0   = (ushort_t*)(ws + 67108864);      // 192 KiB
    ushort_t* wf1   = (ushort_t*)(ws + 67305472);      // 256 KiB
    float*    bp0   = (float*)   (ws + 67567616);      // 2 KiB
    float*    bp1   = (float*)   (ws + 67569664);      // 2 KiB
    float*    lastH = (float*)   (ws + 67571712);      // 512 KiB
    uint32*   flags = (uint32*)  (ws + 68096000);      // 8 KiB (64 flags, 128 B apart)

    prep_frag<0><<<384, 256, 0, stream>>>(Whh0, Wih0, wf0);
    prep_frag<1><<<512, 256, 0, stream>>>(Whh1, Wih1, wf1);
    prep_bias<<<4, 256, 0, stream>>>(bih0, bhh0, bih1, bhh1, bp0, bp1, flags);

    lstm_pipe<<<128, 1024, 0, stream>>>(x, wf0, wf1, bp0, bp1, h1k, lastH, flags);

    head_kernel<<<256, 256, 0, stream>>>(lastH, ln_g, ln_b, fc1w, fc1b, fc2w, fc2b,
                                         (float*)d_out);
}

// Round 16
// 306.720 us; speedup vs baseline: 1.0621x; 1.0621x over previous
//
#include <hip/hip_runtime.h>

typedef unsigned short ushort_t;
typedef unsigned int uint32;
typedef __attribute__((ext_vector_type(8))) short short8;
typedef __attribute__((ext_vector_type(4))) float f32x4;
typedef __attribute__((ext_vector_type(2))) float f32x2;

#define LOG2E   1.4426950408889634f
#define LOG2E2  2.8853900817779268f
#define MFMA16  __builtin_amdgcn_mfma_f32_16x16x32_bf16

static __device__ __forceinline__ ushort_t f2bf(float f) {
    uint32 u = __float_as_uint(f);
    u += 0x7FFFu + ((u >> 16) & 1u);
    return (ushort_t)(u >> 16);
}
static __device__ __forceinline__ float rcp_(float x) { return __builtin_amdgcn_rcpf(x); }
static __device__ __forceinline__ float ex2_(float x) { return __builtin_amdgcn_exp2f(x); }
// sigmoid with pre-scaled arg (x already multiplied by log2e)
static __device__ __forceinline__ float sigp_(float x) { return rcp_(1.0f + ex2_(-x)); }

// LDS-only block sync: does NOT drain vmcnt -> global stores float across steps.
static __device__ __forceinline__ void bar_lds() {
    asm volatile("s_waitcnt lgkmcnt(0)" ::: "memory");
    __builtin_amdgcn_s_barrier();
}

// ---------------- prep: pack W into MFMA A-fragments (16-wave / 2-tile geometry) ----
template<int LAYER>
__global__ void prep_frag(const float* __restrict__ Whh, const float* __restrict__ Wih,
                          ushort_t* __restrict__ wfrag) {
    constexpr int KT  = (LAYER == 0) ? 6 : 8;
    constexpr int DIN = (LAYER == 0) ? 64 : 128;
    int i = blockIdx.x * 256 + threadIdx.x;
    int e    = i & 7;
    int lam  = (i >> 3) & 63;
    int rest = i >> 9;
    int kt    = rest % KT;
    int rest2 = rest / KT;
    int tt = rest2 & 1;
    int w  = rest2 >> 1;
    if (w >= 16) return;
    int ml = lam & 15;
    int kg = lam >> 4;
    int k  = kt * 32 + kg * 8 + e;
    int r  = ml & 3;
    int hc = 8 * w + 2 * (ml >> 2) + tt;
    int row = r * 128 + hc;
    float scale = (r == 2) ? LOG2E2 : LOG2E;
    float v = (k < 128) ? Whh[row * 128 + k] : Wih[row * DIN + (k - 128)];
    wfrag[i] = f2bf(v * scale);
}

__global__ void prep_bias(const float* __restrict__ bih0, const float* __restrict__ bhh0,
                          const float* __restrict__ bih1, const float* __restrict__ bhh1,
                          float* __restrict__ bp0, float* __restrict__ bp1,
                          uint32* __restrict__ flags) {
    int i = blockIdx.x * 256 + threadIdx.x;   // 0..1023
    flags[i] = 0u;                            // reset pipeline flags (graph-replay safe)
    flags[i + 1024] = 0u;
    int p = i & 511;
    int w = p >> 5, tt = (p >> 4) & 1, ml = p & 15;
    int r = ml & 3;
    int hc = 8 * w + 2 * (ml >> 2) + tt;
    int row = r * 128 + hc;
    float scale = (r == 2) ? LOG2E2 : LOG2E;
    if (i < 512) bp0[p] = (bih0[row] + bhh0[row]) * scale;
    else         bp1[p] = (bih1[row] + bhh1[row]) * scale;
}

// ---------------- pipelined 2-layer LSTM, drain-free step loop (round-13 config) ----
// 128 blocks x 1024 threads (16 waves -> 4 waves/SIMD latency self-hiding).
// Blocks 0..63 = L0 producer, 64..127 = L1 consumer (same batch group).
// Step barrier = raw lgkmcnt(0)+s_barrier (no vmcnt drain): producer's agent-scope
// record stores retire in the background. Every 8 steps the producer does a full
// vmcnt(0) drain (all waves) + barrier + release flag = T+1 (records <= T visible).
// Consumer starts at flag >= 16 (~15 us fill = built-in producer lead); its step is
// structurally heavier (16 vs 12 MFMA) so the lead only grows -> steady-state
// consumer rarely polls and runs at solo pace.
// [r14/r15 post-mortem: aged stores and 4-step flags both REGRESS — keep r13 exact.]
template<int KT, bool IS_L0>
__device__ __forceinline__ void run_phase(
    const int blk,
    const float* __restrict__ xin_f32,     // IS_L0: [B,T,64] f32
    const uint32* __restrict__ xin_rec,    // !IS_L0: k-major records
    const ushort_t* __restrict__ wfrag,
    const float* __restrict__ biasp,
    uint32* __restrict__ hout,             // IS_L0 out
    float* __restrict__ lastH,             // !IS_L0 out
    uint32* __restrict__ flagp,
    ushort_t* hb, ushort_t* xb)
{
    constexpr int KX = KT - 4;
    const int tid  = threadIdx.x;
    const int w    = tid >> 6;
    const int lane = tid & 63;
    const int n    = lane & 15;
    const int kg   = lane >> 4;
    const int b0   = blk * 16;

    // weights -> registers (held entire kernel)
    short8 wf[2][KT];
#pragma unroll
    for (int tt = 0; tt < 2; ++tt)
#pragma unroll
        for (int kt = 0; kt < KT; ++kt)
            wf[tt][kt] = *(const short8*)&wfrag[((((w * 2 + tt) * KT) + kt) * 64 + lane) * 8];

    const f32x4 bias0 = *(const f32x4*)&biasp[w * 32 + kg * 4];
    const f32x4 bias1 = *(const f32x4*)&biasp[w * 32 + 16 + kg * 4];

    float cc0 = 0.f, cc1 = 0.f;
    const int hc0 = 8 * w + 2 * kg;        // thread's two h-cols: hc0, hc0+1

    // staging maps
    const int ns  = (tid >> 3) & 15;
    const int kk  = (tid >> 9) * 32 + ((tid >> 7) & 3) * 8 + (tid & 7);
    const long xbase0 = (long)(b0 + ns) * (256 * 64) + kk;
    const long rb     = (long)blk * (256 * 1024);            // u32 units

    uint32*       stp = &hout[rb + w * 64 + n * 4 + kg];     // producer: record 0 slot
    const uint32* ldp = IS_L0 ? nullptr : &xin_rec[rb + 1024 + tid];  // consumer: record 1
    uint32 lastF = 0;

    // prologue: zero h state (parity 0), stage x/rec[0]
    ((uint32*)hb)[tid] = 0u;
    if constexpr (IS_L0) {
        xb[tid] = f2bf(xin_f32[xbase0]);
    } else {
        lastF = __hip_atomic_load(flagp, __ATOMIC_ACQUIRE, __HIP_MEMORY_SCOPE_AGENT);
        while (lastF < 16u) {              // built-in 16-step producer head start
            __builtin_amdgcn_s_sleep(8);
            lastF = __hip_atomic_load(flagp, __ATOMIC_ACQUIRE, __HIP_MEMORY_SCOPE_AGENT);
        }
        ((uint32*)xb)[tid] = __hip_atomic_load(&xin_rec[rb + tid],
                                __ATOMIC_RELAXED, __HIP_MEMORY_SCOPE_AGENT);
    }
    __syncthreads();

#define STEP(CUR, NXT, T)                                                          \
    {                                                                              \
        const bool pf = ((T) + 1 < 256);                                           \
        float xf = 0.f; uint32 xu = 0;                                             \
        if (pf) {                                                                  \
            if (IS_L0) {                                                           \
                xf = xin_f32[xbase0 + ((T) + 1) * 64];                             \
            } else {                                                               \
                const uint32 want = (uint32)((T) + 2);   /* record T+1 */          \
                if (lastF < want) {                                                \
                    lastF = __hip_atomic_load(flagp, __ATOMIC_ACQUIRE, __HIP_MEMORY_SCOPE_AGENT); \
                    while (lastF < want) {                                         \
                        __builtin_amdgcn_s_sleep(4);                               \
                        lastF = __hip_atomic_load(flagp, __ATOMIC_ACQUIRE, __HIP_MEMORY_SCOPE_AGENT); \
                    }                                                              \
                }                                                                  \
                xu = __hip_atomic_load(ldp, __ATOMIC_RELAXED, __HIP_MEMORY_SCOPE_AGENT); \
                ldp += 1024;                                                       \
            }                                                                      \
        }                                                                          \
        short8 bfr0 = *(const short8*)&hb[(CUR) * 2048 + kg * 128 + n * 8];        \
        f32x4 acc0 = MFMA16(wf[0][0], bfr0, bias0, 0, 0, 0);                       \
        f32x4 acc1 = MFMA16(wf[1][0], bfr0, bias1, 0, 0, 0);                       \
        _Pragma("unroll")                                                          \
        for (int kt = 1; kt < 4; ++kt) {                                           \
            short8 bfr = *(const short8*)&hb[(CUR) * 2048 + kt * 512 + kg * 128 + n * 8]; \
            acc0 = MFMA16(wf[0][kt], bfr, acc0, 0, 0, 0);                          \
            acc1 = MFMA16(wf[1][kt], bfr, acc1, 0, 0, 0);                          \
        }                                                                          \
        _Pragma("unroll")                                                          \
        for (int kx = 0; kx < KX; ++kx) {                                          \
            short8 bfr = *(const short8*)&xb[(CUR) * (KX * 512) + kx * 512 + kg * 128 + n * 8]; \
            acc0 = MFMA16(wf[0][4 + kx], bfr, acc0, 0, 0, 0);                      \
            acc1 = MFMA16(wf[1][4 + kx], bfr, acc1, 0, 0, 0);                      \
        }                                                                          \
        float i0 = sigp_(acc0[0]);                                                 \
        float f0 = sigp_(acc0[1]);                                                 \
        float tg0 = fmaf(2.f, sigp_(acc0[2]), -1.f);                               \
        float o0 = sigp_(acc0[3]);                                                 \
        cc0 = fmaf(f0, cc0, i0 * tg0);                                             \
        float h0 = o0 * fmaf(2.f, sigp_(cc0 * LOG2E2), -1.f);                      \
        float i1 = sigp_(acc1[0]);                                                 \
        float f1 = sigp_(acc1[1]);                                                 \
        float tg1 = fmaf(2.f, sigp_(acc1[2]), -1.f);                               \
        float o1 = sigp_(acc1[3]);                                                 \
        cc1 = fmaf(f1, cc1, i1 * tg1);                                             \
        float h1v = o1 * fmaf(2.f, sigp_(cc1 * LOG2E2), -1.f);                     \
        uint32 hp;                                                                 \
        asm("v_cvt_pk_bf16_f32 %0, %1, %2" : "=v"(hp) : "v"(h0), "v"(h1v));        \
        *(uint32*)&hb[(NXT) * 2048 + w * 128 + n * 8 + kg * 2] = hp;               \
        if (!IS_L0 && (T) == 255) {                                                \
            f32x2 hv2 = {h0, h1v};                                                 \
            *(f32x2*)&lastH[(long)(b0 + n) * 128 + hc0] = hv2;                     \
        }                                                                          \
        if (pf) {                                                                  \
            if (IS_L0) xb[(NXT) * (KX * 512) + tid] = f2bf(xf);                    \
            else       ((uint32*)xb)[(NXT) * (KX * 256) + tid] = xu;               \
        }                                                                          \
        if (IS_L0) {                                                               \
            /* record T: agent-scope store, retires in background (no drain) */    \
            __hip_atomic_store(stp, hp, __ATOMIC_RELAXED, __HIP_MEMORY_SCOPE_AGENT); \
            stp += 1024;                                                           \
        }                                                                          \
        bar_lds();                                                                 \
        if (IS_L0 && ((((T) + 1) & 7) == 0)) {                                     \
            /* full drain: every wave waits its own stores, then publish */        \
            asm volatile("s_waitcnt vmcnt(0)" ::: "memory");                       \
            __builtin_amdgcn_s_barrier();                                          \
            if (tid == 0)                                                          \
                __hip_atomic_store(flagp, (uint32)((T) + 1), __ATOMIC_RELEASE, __HIP_MEMORY_SCOPE_AGENT); \
        }                                                                          \
    }

#pragma unroll 1
    for (int t = 0; t < 256; t += 2) {
        STEP(0, 1, t)
        STEP(1, 0, t + 1)
    }
#undef STEP
}

__global__ __launch_bounds__(1024)
void lstm_pipe(const float* __restrict__ x,
               const ushort_t* __restrict__ wf0, const ushort_t* __restrict__ wf1,
               const float* __restrict__ bp0, const float* __restrict__ bp1,
               uint32* __restrict__ h1k, float* __restrict__ lastH,
               uint32* __restrict__ flags)
{
    __shared__ ushort_t hb[4096];   // 8 KiB: h double buffer
    __shared__ ushort_t xb[4096];   // 8 KiB: x double buffer (L0 uses half)
    const int blk = blockIdx.x;
    if (blk < 64)
        run_phase<6, true >(blk, x, nullptr, wf0, bp0, h1k, nullptr,
                            &flags[blk * 32], hb, xb);
    else
        run_phase<8, false>(blk - 64, nullptr, h1k, wf1, bp1, nullptr, lastH,
                            &flags[(blk - 64) * 32], hb, xb);
}

// ---------------- head: LayerNorm + fc1(relu) + fc2 ----------------
__global__ __launch_bounds__(256)
void head_kernel(const float* __restrict__ lastH,
                 const float* __restrict__ ln_g, const float* __restrict__ ln_b,
                 const float* __restrict__ fc1w, const float* __restrict__ fc1b,
                 const float* __restrict__ fc2w, const float* __restrict__ fc2b,
                 float* __restrict__ out) {
    __shared__ float ylds[4][128];
    int w = threadIdx.x >> 6, lane = threadIdx.x & 63;
    int row = blockIdx.x * 4 + w;
    float x0 = lastH[row * 128 + lane];
    float x1 = lastH[row * 128 + 64 + lane];
    float s = x0 + x1;
    for (int off = 32; off; off >>= 1) s += __shfl_xor(s, off);
    float mu = s * (1.f / 128.f);
    float d0 = x0 - mu, d1 = x1 - mu;
    float v = d0 * d0 + d1 * d1;
    for (int off = 32; off; off >>= 1) v += __shfl_xor(v, off);
    float rs = rsqrtf(v * (1.f / 128.f) + 1e-5f);
    ylds[w][lane]      = d0 * rs * ln_g[lane]      + ln_b[lane];
    ylds[w][lane + 64] = d1 * rs * ln_g[lane + 64] + ln_b[lane + 64];
    __syncthreads();
    float a = fc1b[lane];
#pragma unroll 4
    for (int k = 0; k < 128; ++k) a += ylds[w][k] * fc1w[lane * 128 + k];
    float r = fmaxf(a, 0.f) * fc2w[lane];
    for (int off = 32; off; off >>= 1) r += __shfl_xor(r, off);
    if (lane == 0) out[row] = r + fc2b[0];
}

extern "C" void kernel_launch(void* const* d_in, const int* in_sizes, int n_in,
                              void* d_out, int out_size, void* d_ws, size_t ws_size,
                              hipStream_t stream) {
    const float* x    = (const float*)d_in[0];
    const float* Wih0 = (const float*)d_in[1];
    const float* Whh0 = (const float*)d_in[2];
    const float* bih0 = (const float*)d_in[3];
    const float* bhh0 = (const float*)d_in[4];
    const float* Wih1 = (const float*)d_in[5];
    const float* Whh1 = (const float*)d_in[6];
    const float* bih1 = (const float*)d_in[7];
    const float* bhh1 = (const float*)d_in[8];
    const float* ln_g = (const float*)d_in[9];
    const float* ln_b = (const float*)d_in[10];
    const float* fc1w = (const float*)d_in[11];
    const float* fc1b = (const float*)d_in[12];
    const float* fc2w = (const float*)d_in[13];
    const float* fc2b = (const float*)d_in[14];

    char* ws = (char*)d_ws;
    uint32*   h1k   = (uint32*)  (ws);                 // 64 blk x 256 t x 4 KiB = 64 MiB
    ushort_t* wf0   = (ushort_t*)(ws + 67108864);      // 192 KiB
    ushort_t* wf1   = (ushort_t*)(ws + 67305472);      // 256 KiB
    float*    bp0   = (float*)   (ws + 67567616);      // 2 KiB
    float*    bp1   = (float*)   (ws + 67569664);      // 2 KiB
    float*    lastH = (float*)   (ws + 67571712);      // 512 KiB
    uint32*   flags = (uint32*)  (ws + 68096000);      // 8 KiB (64 flags, 128 B apart)

    prep_frag<0><<<384, 256, 0, stream>>>(Whh0, Wih0, wf0);
    prep_frag<1><<<512, 256, 0, stream>>>(Whh1, Wih1, wf1);
    prep_bias<<<4, 256, 0, stream>>>(bih0, bhh0, bih1, bhh1, bp0, bp1, flags);

    lstm_pipe<<<128, 1024, 0, stream>>>(x, wf0, wf1, bp0, bp1, h1k, lastH, flags);

    head_kernel<<<256, 256, 0, stream>>>(lastH, ln_g, ln_b, fc1w, fc1b, fc2w, fc2b,
                                         (float*)d_out);
}